// Round 4
// baseline (1307.136 us; speedup 1.0000x reference)
//
#include <hip/hip_runtime.h>
#include <hip/hip_bf16.h>

#define BATCH 256
#define NDIM  4096
#define STEPS 16
#define EPS_RMS 1.1920929e-07f
#define LSTR2 136   // 128 + 8 fp16 elems pad (row stride 272B -> 2-way-free bank pattern)

typedef _Float16 f16x8 __attribute__((ext_vector_type(8)));
typedef float  f32x4  __attribute__((ext_vector_type(4)));
typedef unsigned short u16x4 __attribute__((ext_vector_type(4)));
typedef unsigned int   u32x4 __attribute__((ext_vector_type(4)));

__device__ __forceinline__ unsigned short f2h(float f) {
  _Float16 h = (_Float16)f;
  union { _Float16 h; unsigned short u; } v; v.h = h; return v.u;
}

// m-group barrier: 64 blocks with the same m-tile. Release/acquire, agent scope.
__device__ __forceinline__ void mbarrier(int* c, int target) {
  __syncthreads();
  if (threadIdx.x == 0) {
    __threadfence();
    __hip_atomic_fetch_add(c, 1, __ATOMIC_RELEASE, __HIP_MEMORY_SCOPE_AGENT);
    while (__hip_atomic_load(c, __ATOMIC_ACQUIRE, __HIP_MEMORY_SCOPE_AGENT) < target)
      __builtin_amdgcn_s_sleep(2);
  }
  __syncthreads();
}

// ---------------- W (f32, [k][n]) -> Wt (fp16, [n][k]) ----------------
__global__ __launch_bounds__(256) void transpose_w(
    const float* __restrict__ W, unsigned short* __restrict__ Wt) {
  __shared__ float tile[64][65];
  int n0 = blockIdx.x * 64;
  int k0 = blockIdx.y * 64;
  int t = threadIdx.x;
  int r = t >> 4, c4 = (t & 15) * 4;
  #pragma unroll
  for (int p = 0; p < 4; ++p) {
    f32x4 v = *(const f32x4*)(W + (size_t)(k0 + r + 16 * p) * NDIM + n0 + c4);
    tile[r + 16 * p][c4 + 0] = v[0];
    tile[r + 16 * p][c4 + 1] = v[1];
    tile[r + 16 * p][c4 + 2] = v[2];
    tile[r + 16 * p][c4 + 3] = v[3];
  }
  __syncthreads();
  #pragma unroll
  for (int p = 0; p < 4; ++p) {
    int nr = r + 16 * p;
    u16x4 o;
    #pragma unroll
    for (int j = 0; j < 4; ++j) o[j] = f2h(tile[c4 + j][nr]);
    *(u16x4*)(Wt + (size_t)(n0 + nr) * NDIM + k0 + c4) = o;
  }
}

// ---------------- column multipliers + barrier-counter zeroing ----------------
__global__ void init_colmul(const float* __restrict__ iscale,
                            const float* __restrict__ oscale,
                            const int* __restrict__ ipos, const int* __restrict__ opos,
                            float* __restrict__ icm, float* __restrict__ ocm,
                            int* __restrict__ cnt) {
  int c = blockIdx.x * 256 + threadIdx.x;
  if (blockIdx.x == 0 && threadIdx.x < 128) cnt[threadIdx.x] = 0;
  if (c >= NDIM) return;
  float iv = 1.f, ov = 1.f;
  #pragma unroll
  for (int i = 0; i < 16; ++i) {
    if (ipos[i] == c) iv *= iscale[i];
    if (opos[i] == c) ov *= oscale[i];
  }
  icm[c] = iv; ocm[c] = ov;
}

// ---------------- persistent cooperative kernel: all 16 steps ----------------
// grid = 256 blocks (1/CU), block = 256 threads (4 waves, 2x2 of 32x32 sub-tiles).
// Block (mt, nt) owns output tile rows mt*64.., cols nt*64.. for every step.
__global__ __launch_bounds__(256) void persistent_kernel(
    const unsigned short* __restrict__ Wt,  // fp16 [n][k]
    unsigned short* __restrict__ hbuf,      // fp16 [256][4096]
    const float* __restrict__ x,
    const float* __restrict__ bias,
    const float* __restrict__ icm,
    const float* __restrict__ nw,
    const float* __restrict__ ocm,
    float* __restrict__ part,               // [2][256][64]
    int* __restrict__ cnt,                  // [4][32]
    float* __restrict__ out,                // [256][16][4096]
    float* __restrict__ hfin) {             // [256][4096]
  __shared__ __align__(16) unsigned short As[64 * LSTR2];
  __shared__ __align__(16) unsigned short Bs[64 * LSTR2];
  __shared__ float ps[2][64];
  __shared__ float scale_s[64];

  const int tid = threadIdx.x;
  const int bid = blockIdx.x;
  const int mt = bid >> 6;           // 0..3
  const int nt = bid & 63;           // 0..63
  const int m0 = mt * 64, n0 = nt * 64;
  const int wave = tid >> 6, lane = tid & 63;
  const int wm = (wave >> 1) * 32, wn = (wave & 1) * 32;
  const int wni = wave & 1;
  const int l15 = lane & 15, lk = (lane >> 4) * 8;
  const int crow = (lane >> 4) * 4;
  const int rowA = tid >> 2, cg = (tid & 3) * 32;  // staging: 4 threads/row, 32-elem chunks
  int* cgrp = cnt + mt * 32;

  for (int t = 0; t < STEPS; ++t) {
    float* pp = part + (size_t)(t & 1) * (BATCH * 64);

    if (t == 0) {
      // ---- inject phase (no GEMM): signal = B + x*icm, linear layout ----
      int r = tid >> 2, q = tid & 3;
      int row = m0 + r;
      float a[16];
      float sq = 0.f;
      #pragma unroll
      for (int j4 = 0; j4 < 4; ++j4) {
        int c = n0 + q * 16 + j4 * 4;
        f32x4 xv = *(const f32x4*)(x + (size_t)row * NDIM + c);
        f32x4 bv = *(const f32x4*)(bias + c);
        f32x4 ic = *(const f32x4*)(icm + c);
        #pragma unroll
        for (int j = 0; j < 4; ++j) {
          float av = tanhf(bv[j] + xv[j] * ic[j]);
          a[j4 * 4 + j] = av;
          sq += av * av;
        }
      }
      sq += __shfl_xor(sq, 1, 64);
      sq += __shfl_xor(sq, 2, 64);
      if (q == 0) pp[(size_t)row * 64 + nt] = sq;
      mbarrier(&cgrp[t * 2], 64);
      // scales for this block's 64 rows
      {
        int rr = tid >> 2, qq = tid & 3;
        const float* pr = pp + (size_t)(m0 + rr) * 64 + qq * 16;
        f32x4 s0 = *(const f32x4*)pr;
        f32x4 s1 = *(const f32x4*)(pr + 4);
        f32x4 s2 = *(const f32x4*)(pr + 8);
        f32x4 s3 = *(const f32x4*)(pr + 12);
        f32x4 st = s0 + s1 + s2 + s3;
        float s = st[0] + st[1] + st[2] + st[3];
        s += __shfl_xor(s, 1, 64);
        s += __shfl_xor(s, 2, 64);
        if (qq == 0) scale_s[rr] = rsqrtf(s * (1.0f / NDIM) + EPS_RMS);
      }
      __syncthreads();
      {
        float sc = scale_s[r];
        #pragma unroll
        for (int j4 = 0; j4 < 4; ++j4) {
          int c = n0 + q * 16 + j4 * 4;
          f32x4 nv = *(const f32x4*)(nw + c);
          f32x4 oc = *(const f32x4*)(ocm + c);
          u16x4 hs; f32x4 os;
          #pragma unroll
          for (int j = 0; j < 4; ++j) {
            float h = a[j4 * 4 + j] * sc * nv[j];
            hs[j] = f2h(h);
            os[j] = h * oc[j];
          }
          *(u16x4*)(hbuf + (size_t)row * NDIM + c) = hs;
          *(f32x4*)(out + ((size_t)row * STEPS + 0) * NDIM + c) = os;
        }
      }
      mbarrier(&cgrp[t * 2 + 1], 64);
      continue;
    }

    // ---- GEMM phase: 64x64 tile, full K=4096, BK=128 ----
    const unsigned short* Ap = hbuf + (size_t)(m0 + rowA) * NDIM;
    const unsigned short* Bp = Wt + (size_t)(n0 + rowA) * NDIM;
    u32x4 aR[4], bR[4];
    #pragma unroll
    for (int v = 0; v < 4; ++v) {
      aR[v] = *(const u32x4*)(Ap + cg + v * 8);
      bR[v] = *(const u32x4*)(Bp + cg + v * 8);
    }
    f32x4 acc[2][2];
    f32x4 zero = {0.f, 0.f, 0.f, 0.f};
    acc[0][0] = zero; acc[0][1] = zero; acc[1][0] = zero; acc[1][1] = zero;

    for (int it = 0; it < 32; ++it) {
      __syncthreads();
      #pragma unroll
      for (int v = 0; v < 4; ++v) {
        *(u32x4*)&As[rowA * LSTR2 + cg + v * 8] = aR[v];
        *(u32x4*)&Bs[rowA * LSTR2 + cg + v * 8] = bR[v];
      }
      __syncthreads();
      if (it < 31) {
        int kb = (it + 1) * 128;
        #pragma unroll
        for (int v = 0; v < 4; ++v) {
          aR[v] = *(const u32x4*)(Ap + kb + cg + v * 8);
          bR[v] = *(const u32x4*)(Bp + kb + cg + v * 8);
        }
      }
      #pragma unroll
      for (int kk = 0; kk < 4; ++kk) {
        f16x8 af[2], bf[2];
        #pragma unroll
        for (int mf = 0; mf < 2; ++mf)
          af[mf] = *(const f16x8*)&As[(wm + mf * 16 + l15) * LSTR2 + kk * 32 + lk];
        #pragma unroll
        for (int nf = 0; nf < 2; ++nf)
          bf[nf] = *(const f16x8*)&Bs[(wn + nf * 16 + l15) * LSTR2 + kk * 32 + lk];
        #pragma unroll
        for (int mf = 0; mf < 2; ++mf)
          #pragma unroll
          for (int nf = 0; nf < 2; ++nf)
            acc[mf][nf] = __builtin_amdgcn_mfma_f32_16x16x32_f16(af[mf], bf[nf], acc[mf][nf], 0, 0, 0);
      }
    }

    // ---- tanh + per-row sum-of-squares partials (fragment layout) ----
    float rs[2][4];
    rs[0][0] = rs[0][1] = rs[0][2] = rs[0][3] = 0.f;
    rs[1][0] = rs[1][1] = rs[1][2] = rs[1][3] = 0.f;
    #pragma unroll
    for (int nf = 0; nf < 2; ++nf) {
      int col = n0 + wn + nf * 16 + l15;
      float bv = bias[col];
      #pragma unroll
      for (int mf = 0; mf < 2; ++mf)
        #pragma unroll
        for (int r = 0; r < 4; ++r) {
          float av = tanhf(acc[mf][nf][r] + bv);
          acc[mf][nf][r] = av;
          rs[mf][r] += av * av;
        }
    }
    #pragma unroll
    for (int mf = 0; mf < 2; ++mf)
      #pragma unroll
      for (int r = 0; r < 4; ++r) {
        float v = rs[mf][r];
        v += __shfl_xor(v, 1, 64);
        v += __shfl_xor(v, 2, 64);
        v += __shfl_xor(v, 4, 64);
        v += __shfl_xor(v, 8, 64);
        rs[mf][r] = v;
      }
    if (l15 == 0) {
      #pragma unroll
      for (int mf = 0; mf < 2; ++mf)
        #pragma unroll
        for (int r = 0; r < 4; ++r)
          ps[wni][wm + mf * 16 + crow + r] = rs[mf][r];
    }
    __syncthreads();
    if (tid < 64) pp[(size_t)(m0 + tid) * 64 + nt] = ps[0][tid] + ps[1][tid];
    mbarrier(&cgrp[t * 2], 64);

    // ---- scales ----
    {
      int rr = tid >> 2, qq = tid & 3;
      const float* pr = pp + (size_t)(m0 + rr) * 64 + qq * 16;
      f32x4 s0 = *(const f32x4*)pr;
      f32x4 s1 = *(const f32x4*)(pr + 4);
      f32x4 s2 = *(const f32x4*)(pr + 8);
      f32x4 s3 = *(const f32x4*)(pr + 12);
      f32x4 st = s0 + s1 + s2 + s3;
      float s = st[0] + st[1] + st[2] + st[3];
      s += __shfl_xor(s, 1, 64);
      s += __shfl_xor(s, 2, 64);
      if (qq == 0) scale_s[rr] = rsqrtf(s * (1.0f / NDIM) + EPS_RMS);
    }
    __syncthreads();

    // ---- epilogue: h = a*scale*nw; write hbuf (fp16), out (f32), hfin ----
    #pragma unroll
    for (int nf = 0; nf < 2; ++nf) {
      int col = n0 + wn + nf * 16 + l15;
      float nwv = nw[col], ocv = ocm[col];
      #pragma unroll
      for (int mf = 0; mf < 2; ++mf)
        #pragma unroll
        for (int r = 0; r < 4; ++r) {
          int rl = wm + mf * 16 + crow + r;
          int row = m0 + rl;
          float h = acc[mf][nf][r] * scale_s[rl] * nwv;
          hbuf[(size_t)row * NDIM + col] = f2h(h);
          out[((size_t)row * STEPS + t) * NDIM + col] = h * ocv;
          if (t == STEPS - 1) hfin[(size_t)row * NDIM + col] = h;
        }
    }
    mbarrier(&cgrp[t * 2 + 1], 64);
  }
}

extern "C" void kernel_launch(void* const* d_in, const int* in_sizes, int n_in,
                              void* d_out, int out_size, void* d_ws, size_t ws_size,
                              hipStream_t stream) {
  (void)in_sizes; (void)n_in; (void)out_size; (void)ws_size;
  const float* x      = (const float*)d_in[0];
  const float* W      = (const float*)d_in[1];
  const float* Bb     = (const float*)d_in[2];
  const float* iscale = (const float*)d_in[3];
  const float* oscale = (const float*)d_in[4];
  const float* nw     = (const float*)d_in[5];
  const int* ipos = (const int*)d_in[6];
  const int* opos = (const int*)d_in[7];
  // d_in[8] = steps (fixed at 16 by the problem spec).

  char* ws = (char*)d_ws;
  unsigned short* Wt   = (unsigned short*)(ws);             // 32 MiB fp16
  unsigned short* hbuf = (unsigned short*)(ws + 33554432);  // 2 MiB fp16
  float* icm           = (float*)(ws + 35651584);           // 16 KiB
  float* ocm           = (float*)(ws + 35667968);           // 16 KiB
  float* part          = (float*)(ws + 35684352);           // 128 KiB
  int*   cnt           = (int*)(ws + 35815424);             // 512 B

  float* out  = (float*)d_out;
  float* hfin = out + (size_t)BATCH * STEPS * NDIM;

  hipLaunchKernelGGL(transpose_w, dim3(64, 64), dim3(256), 0, stream, W, Wt);
  hipLaunchKernelGGL(init_colmul, dim3(16), dim3(256), 0, stream,
                     iscale, oscale, ipos, opos, icm, ocm, cnt);

  void* args[] = { (void*)&Wt, (void*)&hbuf, (void*)&x, (void*)&Bb, (void*)&icm,
                   (void*)&nw, (void*)&ocm, (void*)&part, (void*)&cnt,
                   (void*)&out, (void*)&hfin };
  hipLaunchCooperativeKernel((void*)persistent_kernel, dim3(256), dim3(256),
                             args, 0, stream);
}

// Round 5
// 362.384 us; speedup vs baseline: 3.6070x; 3.6070x over previous
//
#include <hip/hip_runtime.h>
#include <hip/hip_bf16.h>

#define BATCH 256
#define NDIM  4096
#define STEPS 16
#define EPS_RMS 1.1920929e-07f

typedef _Float16 f16x8 __attribute__((ext_vector_type(8)));
typedef float  f32x4  __attribute__((ext_vector_type(4)));
typedef unsigned short u16x4 __attribute__((ext_vector_type(4)));
typedef unsigned int   u32x4 __attribute__((ext_vector_type(4)));

#define AS1 __attribute__((address_space(1)))
#define AS3 __attribute__((address_space(3)))
#define GLDS16(gp, lp) __builtin_amdgcn_global_load_lds( \
    (const AS1 void*)(gp), (AS3 void*)(lp), 16, 0, 0)
#define SBAR() do { asm volatile("" ::: "memory"); \
                    __builtin_amdgcn_s_barrier();  \
                    asm volatile("" ::: "memory"); } while (0)

__device__ __forceinline__ unsigned short f2h(float f) {
  _Float16 h = (_Float16)f;
  union { _Float16 h; unsigned short u; } v; v.h = h; return v.u;
}

__device__ __forceinline__ float block_reduce_sum_512(float v) {
  __shared__ float ws[8];
  __shared__ float tot;
  #pragma unroll
  for (int off = 32; off > 0; off >>= 1) v += __shfl_down(v, off, 64);
  int lane = threadIdx.x & 63, w = threadIdx.x >> 6;
  if (lane == 0) ws[w] = v;
  __syncthreads();
  if (threadIdx.x == 0) {
    float t = 0.f;
    #pragma unroll
    for (int i = 0; i < 8; ++i) t += ws[i];
    tot = t;
  }
  __syncthreads();
  return tot;
}

// ---------------- W (f32, [k][n]) -> Wt (fp16, [n][k]) ----------------
__global__ __launch_bounds__(256) void transpose_w(
    const float* __restrict__ W, unsigned short* __restrict__ Wt) {
  __shared__ float tile[64][65];
  int n0 = blockIdx.x * 64;
  int k0 = blockIdx.y * 64;
  int t = threadIdx.x;
  int r = t >> 4, c4 = (t & 15) * 4;
  #pragma unroll
  for (int p = 0; p < 4; ++p) {
    f32x4 v = *(const f32x4*)(W + (size_t)(k0 + r + 16 * p) * NDIM + n0 + c4);
    tile[r + 16 * p][c4 + 0] = v[0];
    tile[r + 16 * p][c4 + 1] = v[1];
    tile[r + 16 * p][c4 + 2] = v[2];
    tile[r + 16 * p][c4 + 3] = v[3];
  }
  __syncthreads();
  #pragma unroll
  for (int p = 0; p < 4; ++p) {
    int nr = r + 16 * p;
    u16x4 o;
    #pragma unroll
    for (int j = 0; j < 4; ++j) o[j] = f2h(tile[c4 + j][nr]);
    *(u16x4*)(Wt + (size_t)(n0 + nr) * NDIM + k0 + c4) = o;
  }
}

// ---------------- column multipliers from scatter positions ----------------
__global__ void init_colmul(const float* __restrict__ iscale,
                            const float* __restrict__ oscale,
                            const int* __restrict__ ipos, const int* __restrict__ opos,
                            float* __restrict__ icm, float* __restrict__ ocm) {
  int c = blockIdx.x * 256 + threadIdx.x;
  if (c >= NDIM) return;
  float iv = 1.f, ov = 1.f;
  #pragma unroll
  for (int i = 0; i < 16; ++i) {
    if (ipos[i] == c) iv *= iscale[i];
    if (opos[i] == c) ov *= oscale[i];
  }
  icm[c] = iv; ocm[c] = ov;
}

// ---------------- step 0: h1 = norm(tanh(B + x*icm)) ----------------
__global__ __launch_bounds__(512) void step0_kernel(
    const float* __restrict__ x, const float* __restrict__ bias,
    const float* __restrict__ icm, const float* __restrict__ nw,
    const float* __restrict__ ocm,
    unsigned short* __restrict__ hbuf, float* __restrict__ out) {
  int row = blockIdx.x;
  int tid = threadIdx.x;
  const float* xr = x + (size_t)row * NDIM;
  float a[8];
  float sq = 0.f;
  #pragma unroll
  for (int p = 0; p < 2; ++p) {
    int c = p * 2048 + tid * 4;
    f32x4 xv = *(const f32x4*)(xr + c);
    f32x4 bv = *(const f32x4*)(bias + c);
    f32x4 ic = *(const f32x4*)(icm + c);
    #pragma unroll
    for (int j = 0; j < 4; ++j) {
      float av = tanhf(bv[j] + xv[j] * ic[j]);
      a[p * 4 + j] = av;
      sq += av * av;
    }
  }
  float tot = block_reduce_sum_512(sq);
  float scale = rsqrtf(tot * (1.0f / NDIM) + EPS_RMS);
  unsigned short* hrow = hbuf + (size_t)row * NDIM;
  float* orow = out + (size_t)row * STEPS * NDIM;  // t = 0
  #pragma unroll
  for (int p = 0; p < 2; ++p) {
    int c = p * 2048 + tid * 4;
    f32x4 nv = *(const f32x4*)(nw + c);
    f32x4 oc = *(const f32x4*)(ocm + c);
    u16x4 hs; f32x4 os;
    #pragma unroll
    for (int j = 0; j < 4; ++j) {
      float h = a[p * 4 + j] * scale * nv[j];
      hs[j] = f2h(h);
      os[j] = h * oc[j];
    }
    *(u16x4*)(hrow + c) = hs;
    *(f32x4*)(orow + c) = os;
  }
}

// ---------------- GEMM: pbuf[ks] = (h @ W)[64x128 tile, K-slice 1024] ----------------
// grid (32, 4, 4) = 512 blocks (2/CU), 256 threads (4 waves, 2x2 wave grid).
// global_load_lds(16B) staging, chunk-swizzled (c ^= row&7), double-buffered LDS,
// counted vmcnt(6) + raw s_barrier (loads stay in flight across barriers).
__global__ __launch_bounds__(256, 2) void gemm_kernel(
    const unsigned short* __restrict__ A,   // h fp16 [256][4096]
    const unsigned short* __restrict__ Bt,  // Wt fp16 [n][k]
    float* __restrict__ pbuf) {             // [4][256][4096] f32
  __shared__ __align__(16) unsigned short As[2][64 * 64];
  __shared__ __align__(16) unsigned short Bs[2][128 * 64];
  const int tid = threadIdx.x;
  const int n0 = blockIdx.x * 128;
  const int m0 = blockIdx.y * 64;
  const int ks = blockIdx.z;
  const int kbase = ks * 1024;
  const int wave = tid >> 6, lane = tid & 63;
  const int wm = (wave >> 1) * 32, wn = (wave & 1) * 64;
  const int l15 = lane & 15;
  const int g = lane >> 4;               // 0..3 (K-group of fragment)
  const int q = l15 & 7;                 // row&7 for swizzle on read side
  const int rho = lane >> 3;             // 0..7 staging row within 8-row issue
  const int koff = ((lane & 7) ^ rho) * 8;  // swizzled K-chunk (elems)

  // per-lane global source row pointers (advance by k each iter)
  const unsigned short* aP[2];
  const unsigned short* bP[4];
  #pragma unroll
  for (int i = 0; i < 2; ++i)
    aP[i] = A + (size_t)(m0 + wave * 16 + i * 8 + rho) * NDIM + kbase + koff;
  #pragma unroll
  for (int i = 0; i < 4; ++i)
    bP[i] = Bt + (size_t)(n0 + wave * 32 + i * 8 + rho) * NDIM + kbase + koff;

  f32x4 acc[2][4];
  f32x4 zero = {0.f, 0.f, 0.f, 0.f};
  #pragma unroll
  for (int i = 0; i < 2; ++i)
    #pragma unroll
    for (int j = 0; j < 4; ++j) acc[i][j] = zero;

  // prologue: stage k-tile 0 into buffer 0
  #pragma unroll
  for (int i = 0; i < 2; ++i)
    GLDS16(aP[i], &As[0][(wave * 16 + i * 8) * 64]);
  #pragma unroll
  for (int i = 0; i < 4; ++i)
    GLDS16(bP[i], &Bs[0][(wave * 32 + i * 8) * 64]);

  for (int it = 0; it < 16; ++it) {
    const int p = it & 1;
    SBAR();   // all waves done reading buf[1-p] -> safe to overwrite
    if (it < 15) {
      const int kb = (it + 1) * 64;
      #pragma unroll
      for (int i = 0; i < 2; ++i)
        GLDS16(aP[i] + kb, &As[1 - p][(wave * 16 + i * 8) * 64]);
      #pragma unroll
      for (int i = 0; i < 4; ++i)
        GLDS16(bP[i] + kb, &Bs[1 - p][(wave * 32 + i * 8) * 64]);
      asm volatile("s_waitcnt vmcnt(6)" ::: "memory");   // buf[p] landed (mine)
    } else {
      asm volatile("s_waitcnt vmcnt(0)" ::: "memory");
    }
    SBAR();   // buf[p] landed for ALL waves
    #pragma unroll
    for (int kk = 0; kk < 2; ++kk) {
      f16x8 af[2], bfr[4];
      #pragma unroll
      for (int mf = 0; mf < 2; ++mf) {
        int row = wm + mf * 16 + l15;
        af[mf] = *(const f16x8*)&As[p][row * 64 + (((kk << 2) + g) ^ q) * 8];
      }
      #pragma unroll
      for (int nf = 0; nf < 4; ++nf) {
        int row = wn + nf * 16 + l15;
        bfr[nf] = *(const f16x8*)&Bs[p][row * 64 + (((kk << 2) + g) ^ q) * 8];
      }
      #pragma unroll
      for (int mf = 0; mf < 2; ++mf)
        #pragma unroll
        for (int nf = 0; nf < 4; ++nf)
          acc[mf][nf] = __builtin_amdgcn_mfma_f32_16x16x32_f16(af[mf], bfr[nf], acc[mf][nf], 0, 0, 0);
    }
  }

  float* pout = pbuf + (size_t)ks * BATCH * NDIM;
  const int crow = (lane >> 4) * 4;
  #pragma unroll
  for (int mf = 0; mf < 2; ++mf) {
    #pragma unroll
    for (int nf = 0; nf < 4; ++nf) {
      int col = n0 + wn + nf * 16 + l15;
      #pragma unroll
      for (int r = 0; r < 4; ++r) {
        int row = m0 + wm + mf * 16 + crow + r;
        pout[(size_t)row * NDIM + col] = acc[mf][nf][r];
      }
    }
  }
}

// ---------------- combine splits + bias + tanh + RMSNorm + outputs ----------------
__global__ __launch_bounds__(512) void normalize_kernel(
    const float* __restrict__ pbuf, const float* __restrict__ bias,
    const float* __restrict__ nw, const float* __restrict__ ocm,
    unsigned short* __restrict__ hbuf, float* __restrict__ out,
    float* __restrict__ hfin, int t, int is_last) {
  const size_t SL = (size_t)BATCH * NDIM;
  int row = blockIdx.x;
  int tid = threadIdx.x;
  const float* p0 = pbuf + (size_t)row * NDIM;
  float a[8];
  float sq = 0.f;
  #pragma unroll
  for (int p = 0; p < 2; ++p) {
    int c = p * 2048 + tid * 4;
    f32x4 s = *(const f32x4*)(p0 + c);
    s += *(const f32x4*)(p0 + SL + c);
    s += *(const f32x4*)(p0 + 2 * SL + c);
    s += *(const f32x4*)(p0 + 3 * SL + c);
    f32x4 bv = *(const f32x4*)(bias + c);
    #pragma unroll
    for (int j = 0; j < 4; ++j) {
      float av = tanhf(s[j] + bv[j]);
      a[p * 4 + j] = av;
      sq += av * av;
    }
  }
  float tot = block_reduce_sum_512(sq);
  float scale = rsqrtf(tot * (1.0f / NDIM) + EPS_RMS);
  unsigned short* hrow = hbuf + (size_t)row * NDIM;
  float* orow = out + ((size_t)row * STEPS + t) * NDIM;
  #pragma unroll
  for (int p = 0; p < 2; ++p) {
    int c = p * 2048 + tid * 4;
    f32x4 nv = *(const f32x4*)(nw + c);
    f32x4 oc = *(const f32x4*)(ocm + c);
    u16x4 hs; f32x4 os; f32x4 hv;
    #pragma unroll
    for (int j = 0; j < 4; ++j) {
      float h = a[p * 4 + j] * scale * nv[j];
      hv[j] = h;
      hs[j] = f2h(h);
      os[j] = h * oc[j];
    }
    *(u16x4*)(hrow + c) = hs;
    *(f32x4*)(orow + c) = os;
    if (is_last) *(f32x4*)(hfin + (size_t)row * NDIM + c) = hv;
  }
}

extern "C" void kernel_launch(void* const* d_in, const int* in_sizes, int n_in,
                              void* d_out, int out_size, void* d_ws, size_t ws_size,
                              hipStream_t stream) {
  (void)in_sizes; (void)n_in; (void)out_size; (void)ws_size;
  const float* x      = (const float*)d_in[0];
  const float* W      = (const float*)d_in[1];
  const float* Bb     = (const float*)d_in[2];
  const float* iscale = (const float*)d_in[3];
  const float* oscale = (const float*)d_in[4];
  const float* nw     = (const float*)d_in[5];
  const int* ipos = (const int*)d_in[6];
  const int* opos = (const int*)d_in[7];
  // d_in[8] = steps (fixed at 16 by the problem spec).

  char* ws = (char*)d_ws;
  unsigned short* Wt   = (unsigned short*)(ws);             // 32 MiB fp16
  unsigned short* hbuf = (unsigned short*)(ws + 33554432);  // 2 MiB fp16
  float* icm           = (float*)(ws + 35651584);           // 16 KiB
  float* ocm           = (float*)(ws + 35667968);           // 16 KiB
  float* pbuf          = (float*)(ws + 35684352);           // 16 MiB (4 slices)

  float* out  = (float*)d_out;
  float* hfin = out + (size_t)BATCH * STEPS * NDIM;

  hipLaunchKernelGGL(transpose_w, dim3(64, 64), dim3(256), 0, stream, W, Wt);
  hipLaunchKernelGGL(init_colmul, dim3(16), dim3(256), 0, stream,
                     iscale, oscale, ipos, opos, icm, ocm);
  hipLaunchKernelGGL(step0_kernel, dim3(256), dim3(512), 0, stream,
                     x, Bb, icm, nw, ocm, hbuf, out);
  for (int t = 1; t < STEPS; ++t) {
    hipLaunchKernelGGL(gemm_kernel, dim3(32, 4, 4), dim3(256), 0, stream,
                       hbuf, Wt, pbuf);
    hipLaunchKernelGGL(normalize_kernel, dim3(256), dim3(512), 0, stream,
                       pbuf, Bb, nw, ocm, hbuf, out, hfin, t, (t == STEPS - 1) ? 1 : 0);
  }
}